// Round 1
// baseline (462.282 us; speedup 1.0000x reference)
//
#include <hip/hip_runtime.h>

// B=4096 rows, N=16384 neurons, F=16384 features.
//
// Restructure vs previous version: the mean is computed WITHOUT the gather,
// via  mean_b = (1/N) * dot(enc[b,:], c)  where c[f] = sum of w[n] over
// neurons preferring feature f (pref is row-invariant). A tiny preamble
// kernel builds c once per launch; the main kernel fuses the dot into the
// LDS staging loop, reduces with ONE barrier (partials through a private
// global slot), then does a single fused gather->fma->relu->store pass.
// This removes the v[32] register-resident pass, 3 barriers and a serial
// reduction tail from the per-block critical path.

constexpr int B_ROWS  = 4096;
constexpr int N_NEUR  = 16384;
constexpr int F_FEAT  = 16384;
constexpr int THREADS = 512;
constexpr int WAVES   = THREADS / 64;        // 8
constexpr int VPT     = N_NEUR / THREADS;    // 32 outputs per thread
constexpr int ITERS   = VPT / 4;             // 8 float4 iterations
constexpr int F_ITER  = F_FEAT / 4 / THREADS;// 8 staging iterations
constexpr float MEAN_SUB = 0.1f;

// ---------------------------------------------------------------------------
// Kernel 1: c[f] = sum_{n: pref[n]==f} w[n].  One block, LDS histogram.
// ---------------------------------------------------------------------------
__global__ void __launch_bounds__(1024)
build_c(const float* __restrict__ w,
        const int*   __restrict__ pref,
        float*       __restrict__ c) {
    __shared__ __align__(16) float cs[F_FEAT];   // 64 KB
    const int tid = threadIdx.x;

    #pragma unroll
    for (int i = 0; i < F_FEAT / 1024; ++i)
        cs[tid + i * 1024] = 0.0f;
    __syncthreads();

    #pragma unroll
    for (int i = 0; i < N_NEUR / 1024; ++i) {
        const int n = tid + i * 1024;
        atomicAdd(&cs[pref[n] & (F_FEAT - 1)], w[n]);
    }
    __syncthreads();

    float4*       c4  = (float4*)c;
    const float4* cs4 = (const float4*)cs;
    #pragma unroll
    for (int i = 0; i < F_FEAT / 4 / 1024; ++i)
        c4[tid + i * 1024] = cs4[tid + i * 1024];
}

// ---------------------------------------------------------------------------
// Kernel 2: stage row + fused dot with c -> 1 barrier -> gather/relu/store.
// ---------------------------------------------------------------------------
__global__ void __launch_bounds__(THREADS, 4)
sensory_fused(const float* __restrict__ enc,
              const float* __restrict__ w,
              const int*   __restrict__ pref,
              const float* __restrict__ c,
              float*       __restrict__ msum,   // [B_ROWS * WAVES] scratch
              float*       __restrict__ out) {
    __shared__ __align__(16) float row[F_FEAT];  // 64 KB; 2 blocks/CU

    const int tid = threadIdx.x;
    const int b   = blockIdx.x;

    // ---- stage enc[b,:] into LDS, fused dot with c (mean precursor) ----
    const float4* __restrict__ rowg4 = (const float4*)(enc + (size_t)b * F_FEAT);
    const float4* __restrict__ c4    = (const float4*)c;
    float4* row4 = (float4*)row;

    float dot = 0.0f;
    #pragma unroll
    for (int j = 0; j < F_ITER; ++j) {
        const int i = tid + j * THREADS;
        const float4 e  = rowg4[i];
        const float4 cc = c4[i];
        row4[i] = e;
        dot = fmaf(e.x, cc.x, fmaf(e.y, cc.y, fmaf(e.z, cc.z, fmaf(e.w, cc.w, dot))));
    }

    // ---- wave reduce; partials through private global slot (one barrier) ----
    #pragma unroll
    for (int off = 32; off > 0; off >>= 1)
        dot += __shfl_down(dot, off, 64);
    if ((tid & 63) == 0)
        msum[b * WAVES + (tid >> 6)] = dot;

    __syncthreads();   // drains vmcnt+lgkmcnt: row staged AND partials visible

    const float4 s0 = *(const float4*)(msum + (size_t)b * WAVES);
    const float4 s1 = *(const float4*)(msum + (size_t)b * WAVES + 4);
    const float sub = (((s0.x + s0.y) + (s0.z + s0.w)) +
                       ((s1.x + s1.y) + (s1.z + s1.w))) * (MEAN_SUB / (float)N_NEUR);

    // ---- fused gather * weight - sub, relu, coalesced float4 store ----
    float* __restrict__ outrow = out + (size_t)b * N_NEUR;
    #pragma unroll
    for (int k = 0; k < ITERS; ++k) {
        const int n = k * (THREADS * 4) + tid * 4;
        const int4   p4 = *(const int4*)(pref + n);
        const float4 w4 = *(const float4*)(w + n);
        float4 o;
        o.x = fmaxf(fmaf(row[p4.x & (F_FEAT - 1)], w4.x, -sub), 0.0f);
        o.y = fmaxf(fmaf(row[p4.y & (F_FEAT - 1)], w4.y, -sub), 0.0f);
        o.z = fmaxf(fmaf(row[p4.z & (F_FEAT - 1)], w4.z, -sub), 0.0f);
        o.w = fmaxf(fmaf(row[p4.w & (F_FEAT - 1)], w4.w, -sub), 0.0f);
        *(float4*)(outrow + n) = o;
    }
}

extern "C" void kernel_launch(void* const* d_in, const int* in_sizes, int n_in,
                              void* d_out, int out_size, void* d_ws, size_t ws_size,
                              hipStream_t stream) {
    const float* enc  = (const float*)d_in[0];   // [B, F] f32
    const float* w    = (const float*)d_in[1];   // [N] f32
    const int*   pref = (const int*)d_in[2];     // [N] i32
    float*       out  = (float*)d_out;           // [B, N] f32

    float* c    = (float*)d_ws;                  // [F]          64 KB
    float* msum = c + F_FEAT;                    // [B * WAVES] 128 KB

    build_c<<<1, 1024, 0, stream>>>(w, pref, c);
    sensory_fused<<<B_ROWS, THREADS, 0, stream>>>(enc, w, pref, c, msum, out);
}